// Round 10
// baseline (228.612 us; speedup 1.0000x reference)
//
#include <hip/hip_runtime.h>
#include <stdint.h>

// B=2, S=2048, H=1024, NH=16, DK=DV=64, M=4096.
// prologue(cast/transpose/padbits) -> QKV gemm (fragment-ready layouts, LDS-repacked
// coalesced epilogue stores; Q pre-scaled by 0.125*log2e) -> barrier-free split-K flash
// attn -> merge -> out gemm (LDS-repacked fp32 epilogue).
// Tiled layouts (u16):
//   Qt[((bh*64+qt)*4 + n*2 + kh)*512 + ln*8 + e]   qt=q>>5, n=(q&31)>>4, frag B-operand
//   Kt[((bh*32+j)*8 + kh*4 + m)*512 + ln*8 + e]    j=k>>6,  m=(k&63)>>4, frag A-operand
//   Vt[((bh*32+j)*8 + kh*4 + md)*512 + ln*8 + e]   V^T frag A-operand (row=d, col=k)
// ws (u16): X(4.19M) WqkvT(3.15M) WoT(1.05M) Qt,Kt,Vt(4.19M ea) Opart(10.49M); Lpart
// overlays dead WqkvT. padbits in tail of d_out.

typedef unsigned short u16;
typedef __attribute__((ext_vector_type(8))) __bf16 bf16x8;
typedef __attribute__((ext_vector_type(4))) float f32x4;

#define SCL 0.18033688011112042f  // 0.125 * log2(e), folded into Q at projection

__device__ __forceinline__ u16 f2bf(float f) {
  union { float f; uint32_t u; } v; v.f = f;
  uint32_t r = v.u + 0x7FFFu + ((v.u >> 16) & 1u);  // RNE
  return (u16)(r >> 16);
}

__device__ __forceinline__ void gl_lds16(const u16* g, u16* l) {
  auto gp = reinterpret_cast<const __attribute__((address_space(1))) uint32_t*>(
      reinterpret_cast<uintptr_t>(g));
  auto lp = reinterpret_cast<__attribute__((address_space(3))) uint32_t*>(
      reinterpret_cast<uintptr_t>(l));
  __builtin_amdgcn_global_load_lds(gp, lp, 16, 0, 0);
}

// ---------------- fused prologue ----------------
__global__ void k_prologue(const float* __restrict__ batch, const int* __restrict__ ids,
                           const float* __restrict__ W_Q, const float* __restrict__ W_K,
                           const float* __restrict__ W_V, const float* __restrict__ W_O,
                           u16* __restrict__ Xbf, u16* __restrict__ dqkv, u16* __restrict__ dwo,
                           unsigned long long* __restrict__ pb) {
  __shared__ float tile[32][33];
  const int bx = blockIdx.x, t = threadIdx.x;
  if (bx < 4096) {
    int idx = (bx * 256 + t) * 4;
    const float4 v = *reinterpret_cast<const float4*>(batch + idx);
    uint2 o;
    o.x = (uint32_t)f2bf(v.x) | ((uint32_t)f2bf(v.y) << 16);
    o.y = (uint32_t)f2bf(v.z) | ((uint32_t)f2bf(v.w) << 16);
    *reinterpret_cast<uint2*>(Xbf + idx) = o;
  } else if (bx < 8192) {
    int b2 = bx - 4096;
    int z = b2 >> 10;
    b2 &= 1023;
    const float* src = z == 0 ? W_Q : (z == 1 ? W_K : (z == 2 ? W_V : W_O));
    u16* dst = z < 3 ? dqkv + (size_t)z * 1024 * 1024 : dwo;
    int c0 = (b2 & 31) * 32, r0 = (b2 >> 5) * 32;
    int tx = t & 31, ty = t >> 5;
#pragma unroll
    for (int i = 0; i < 4; ++i)
      tile[ty + i * 8][tx] = src[(size_t)(r0 + ty + i * 8) * 1024 + c0 + tx];
    __syncthreads();
#pragma unroll
    for (int i = 0; i < 4; ++i)
      dst[(size_t)(c0 + ty + i * 8) * 1024 + r0 + tx] = f2bf(tile[tx][ty + i * 8]);
  } else {
    int idx = (bx - 8192) * 4 + (t >> 6);
    int ln = t & 63;
    int b = idx >> 5, j = idx & 31;
    unsigned long long m = __ballot(ids[b * 2048 + j * 64 + ln] == 0);
    if (ln == 0) pb[idx] = m;
  }
}

// ---------------- GEMM core (m97 structure) ----------------

__device__ __forceinline__ void gemm_tile_acc(
    const u16* __restrict__ A, const u16* __restrict__ Bt, int K,
    int tm, int tn, u16* As, u16* Bs, f32x4 acc[4][4]) {
  const int t = threadIdx.x, wv = t >> 6, ln = t & 63;
  const int wr = (wv & 1) * 64, wc = (wv >> 1) * 64;
  const int lr = ln & 15, q8 = (ln >> 4) * 8;
  const int srow = ln >> 2, scol = (ln & 3) * 8;

  for (int k0 = 0; k0 < K; k0 += 32) {
#pragma unroll
    for (int i = 0; i < 2; ++i) {
      int c = wv + i * 4;
      gl_lds16(A + (size_t)(tm + c * 16 + srow) * K + k0 + scol, As + c * 512 + ln * 8);
      gl_lds16(Bt + (size_t)(tn + c * 16 + srow) * K + k0 + scol, Bs + c * 512 + ln * 8);
    }
    __syncthreads();
    bf16x8 av[4], bv[4];
#pragma unroll
    for (int m = 0; m < 4; ++m)
      av[m] = *reinterpret_cast<const bf16x8*>(As + (wr + m * 16 + lr) * 32 + q8);
#pragma unroll
    for (int n = 0; n < 4; ++n)
      bv[n] = *reinterpret_cast<const bf16x8*>(Bs + (wc + n * 16 + lr) * 32 + q8);
#pragma unroll
    for (int m = 0; m < 4; ++m)
#pragma unroll
      for (int n = 0; n < 4; ++n)
        acc[m][n] = __builtin_amdgcn_mfma_f32_16x16x32_bf16(av[m], bv[n], acc[m][n], 0, 0, 0);
    __syncthreads();
  }
}

// QKV projection into fragment-ready tiled layouts; Q/K epilogue repacked via LDS
// so every global store is a coalesced dwordx4.
__global__ __launch_bounds__(256) void k_qkv(
    const u16* __restrict__ X, const u16* __restrict__ Wt,
    const float* __restrict__ bQ, const float* __restrict__ bK, const float* __restrict__ bV,
    u16* __restrict__ Qt, u16* __restrict__ Kt, u16* __restrict__ Vt) {
  __shared__ __align__(16) u16 SH[9216];  // 18 KB: gemm staging (16 KB) then repack tile
  u16* As = SH;
  u16* Bs = SH + 4096;
  f32x4 acc[4][4] = {};
  const int tm = blockIdx.x * 128, tn = blockIdx.y * 128;
  gemm_tile_acc(X, Wt, 1024, tm, tn, As, Bs, acc);

  const int t = threadIdx.x, wv = t >> 6, ln = t & 63;
  const int wr = (wv & 1) * 64, wc = (wv >> 1) * 64;
  const int lr = ln & 15, q4 = (ln >> 4) * 4;
  const int which = tn >> 10;

  if (which < 2) {  // Q (pre-scaled) / K : LDS repack, 2 feature-half passes
    u16* dstA = which == 0 ? Qt : Kt;
    const float* bias = which == 0 ? bQ : bK;
    for (int p = 0; p < 2; ++p) {
      __syncthreads();
      if ((wv >> 1) == p) {  // this wave-pair owns feature half p
#pragma unroll
        for (int n = 0; n < 4; ++n) {
          int fl = n * 16 + lr;                       // feature within half
          int f = (tn + p * 64 + fl) & 1023;
          float bb = bias[f];
#pragma unroll
          for (int m = 0; m < 4; ++m)
#pragma unroll
            for (int r = 0; r < 4; ++r) {
              int st = wr + m * 16 + q4 + r;          // token within tile
              float v = acc[m][n][r] + bb;
              if (which == 0) v *= SCL;
              SH[st * 72 + fl] = f2bf(v);
            }
        }
      }
      __syncthreads();
      // coalesced store: 16 chunks of 512 u16; thread t -> chunk t>>4, 4 dwordx4
      int ch = t >> 4;
      int qt_l = ch >> 2, nq = (ch >> 1) & 1, kh = ch & 1;
      int tl = t & 15, qq = tl >> 2;
      int hh = ((tn & 1023) >> 6) + p;
#pragma unroll
      for (int i = 0; i < 4; ++i) {
        int s16 = (tl & 3) * 4 + i;
        int st = qt_l * 32 + nq * 16 + s16;
        int fl0 = kh * 32 + qq * 8;
        uint4 v = *reinterpret_cast<const uint4*>(SH + st * 72 + fl0);
        int gr = tm + st;
        int b = gr >> 11, s = gr & 2047;
        int bh = b * 16 + hh;
        size_t base;
        if (which == 0)
          base = ((size_t)((bh * 64 + (s >> 5)) * 4 + ((s & 31) >> 4) * 2 + kh)) << 9;
        else
          base = ((size_t)((bh * 32 + (s >> 6)) * 8 + kh * 4 + ((s & 63) >> 4))) << 9;
        *reinterpret_cast<uint4*>(dstA + base + ((s & 15) + 16 * qq) * 8) = v;
      }
    }
  } else {  // V -> V^T fragment tiles, 4 contiguous k-elems per packed store
#pragma unroll
    for (int n = 0; n < 4; ++n) {
      int f = (tn + wc + n * 16 + lr) & 1023;
      float bb = bV[f];
      int h = f >> 6, dd = f & 63;
      int md = dd >> 4, lrv = dd & 15;
#pragma unroll
      for (int m = 0; m < 4; ++m) {
        int gr0 = tm + wr + m * 16 + q4;
        int b = gr0 >> 11, s0 = gr0 & 2047;
        int bh = b * 16 + h;
        int j = s0 >> 6, kh = (s0 & 63) >> 5, qv = (s0 & 31) >> 3, e0 = s0 & 7;
        size_t addr = (((size_t)(bh * 32 + j) * 8 + kh * 4 + md) << 9) +
                      (lrv + 16 * qv) * 8 + e0;
        uint2 pk;
        pk.x = (uint32_t)f2bf(acc[m][n][0] + bb) | ((uint32_t)f2bf(acc[m][n][1] + bb) << 16);
        pk.y = (uint32_t)f2bf(acc[m][n][2] + bb) | ((uint32_t)f2bf(acc[m][n][3] + bb) << 16);
        *reinterpret_cast<uint2*>(Vt + addr) = pk;
      }
    }
  }
}

// Output projection -> fp32 out; LDS-repacked epilogue (4 quarter passes, dwordx4 stores)
__global__ __launch_bounds__(256) void k_out(
    const u16* __restrict__ O, const u16* __restrict__ WoT,
    const float* __restrict__ bO, float* __restrict__ out) {
  __shared__ __align__(16) u16 SH[9216];
  u16* As = SH;
  u16* Bs = SH + 4096;
  f32x4 acc[4][4] = {};
  const int tm = blockIdx.x * 128, tn = blockIdx.y * 128;
  gemm_tile_acc(O, WoT, 1024, tm, tn, As, Bs, acc);

  const int t = threadIdx.x, wv = t >> 6, ln = t & 63;
  const int wr = (wv & 1) * 64, wc = (wv >> 1) * 64;
  const int lr = ln & 15, q4 = (ln >> 4) * 4;
  float* T2 = reinterpret_cast<float*>(SH);  // 128 x 36 fp32 (18432 B)

  for (int q = 0; q < 4; ++q) {
    __syncthreads();
    if ((wv >> 1) == (q >> 1)) {  // wave-pair owning this feature quarter
#pragma unroll
      for (int nn = 0; nn < 2; ++nn) {
        int n = (q & 1) * 2 + nn;
        int gc = tn + wc + n * 16 + lr;
        float bb = bO[gc];
        int fl = nn * 16 + lr;
#pragma unroll
        for (int m = 0; m < 4; ++m)
#pragma unroll
          for (int r = 0; r < 4; ++r) {
            int st = wr + m * 16 + q4 + r;
            T2[st * 36 + fl] = acc[m][n][r] + bb;
          }
      }
    }
    __syncthreads();
    int st = t >> 1;
#pragma unroll
    for (int i = 0; i < 4; ++i) {
      int fl0 = (t & 1) * 16 + i * 4;
      float4 v = *reinterpret_cast<const float4*>(T2 + st * 36 + fl0);
      *reinterpret_cast<float4*>(out + (size_t)(tm + st) * 1024 + tn + q * 32 + fl0) = v;
    }
  }
}

// ---------------- barrier-free split-K flash attention (R7 body + j=31 skip) ----------------
__global__ __launch_bounds__(128) void k_attn(
    const u16* __restrict__ Qt, const u16* __restrict__ Kt, const u16* __restrict__ Vt,
    const unsigned long long* __restrict__ padbits,
    u16* __restrict__ Opart, float* __restrict__ Lpart) {
  __shared__ __align__(16) u16 Ps[64 * 72];

  const int id = blockIdx.x;
  const int bh = id & 31;
  const int w = 79 - (id >> 5);
  int qi, c;
  if (w < 8)       { qi = w;                   c = 0; }
  else if (w < 24) { qi = 8 + ((w - 8) >> 1);  c = (w - 8) & 1; }
  else if (w < 48) { qi = 16 + (w - 24) / 3;   c = (w - 24) % 3; }
  else             { qi = 24 + ((w - 48) >> 2); c = (w - 48) & 3; }
  const int jts = c * 8;
  int jte = min(qi + 1, jts + 8);
  const int slot = bh * 80 + w;
  const int bI = bh >> 4;
  // exact skip: final tile fully padded contributes nothing
  if (jte == 32 && padbits[bI * 32 + 31] == ~0ull) jte = 31;

  const int t = threadIdx.x, wv = t >> 6, ln = t & 63;
  const int lr = ln & 15, q4 = (ln >> 4) * 4, q8 = (ln >> 4) * 8;
  const int qbase = qi * 64 + wv * 32;
  const int qrow = wv * 32;

  // Q B-frags: coalesced from Qt
  bf16x8 bq[2][2];
  {
    const u16* qb = Qt + (((size_t)(bh * 64 + (qbase >> 5)) * 4) << 9) + ln * 8;
#pragma unroll
    for (int n = 0; n < 2; ++n)
#pragma unroll
      for (int kh = 0; kh < 2; ++kh)
        bq[n][kh] = *reinterpret_cast<const bf16x8*>(qb + ((n * 2 + kh) << 9));
  }

  float lo[2] = {0.f, 0.f};
  f32x4 Oc[4][2] = {};

  const u16* Kb = Kt + (((size_t)bh * 32) << 12) + ln * 8;
  const u16* Vb = Vt + (((size_t)bh * 32) << 12) + ln * 8;

  // preload K frags for first tile
  bf16x8 ak0[4], ak1[4];
#pragma unroll
  for (int m = 0; m < 4; ++m) {
    ak0[m] = *reinterpret_cast<const bf16x8*>(Kb + ((size_t)jts << 12) + (m << 9));
    ak1[m] = *reinterpret_cast<const bf16x8*>(Kb + ((size_t)jts << 12) + ((4 + m) << 9));
  }

  for (int j = jts; j < jte; ++j) {
    const int kb = j * 64;
    const unsigned long long pb = padbits[bI * 32 + j];
    const bool masked = (kb + 63 > qbase) || (pb != 0);

    // V frags for this tile (consumed at PV — latency hidden by S+softmax)
    bf16x8 av0[4], av1[4];
#pragma unroll
    for (int md = 0; md < 4; ++md) {
      av0[md] = *reinterpret_cast<const bf16x8*>(Vb + ((size_t)j << 12) + (md << 9));
      av1[md] = *reinterpret_cast<const bf16x8*>(Vb + ((size_t)j << 12) + ((4 + md) << 9));
    }
    // next tile's K frags (register rotation)
    bf16x8 nk0[4], nk1[4];
    if (j + 1 < jte) {
#pragma unroll
      for (int m = 0; m < 4; ++m) {
        nk0[m] = *reinterpret_cast<const bf16x8*>(Kb + ((size_t)(j + 1) << 12) + (m << 9));
        nk1[m] = *reinterpret_cast<const bf16x8*>(Kb + ((size_t)(j + 1) << 12) + ((4 + m) << 9));
      }
    }

    // S'^T = K (Q*SCL)^T
    f32x4 sc[4][2] = {};
#pragma unroll
    for (int m = 0; m < 4; ++m)
#pragma unroll
      for (int n = 0; n < 2; ++n) {
        sc[m][n] = __builtin_amdgcn_mfma_f32_16x16x32_bf16(ak0[m], bq[n][0], sc[m][n], 0, 0, 0);
        sc[m][n] = __builtin_amdgcn_mfma_f32_16x16x32_bf16(ak1[m], bq[n][1], sc[m][n], 0, 0, 0);
      }

    // fixed-max softmax: p = exp2(s'), lane-local l
#pragma unroll
    for (int n = 0; n < 2; ++n) {
      if (masked) {
        const int qabs = qbase + n * 16 + lr;
#pragma unroll
        for (int m = 0; m < 4; ++m)
#pragma unroll
          for (int r = 0; r < 4; ++r) {
            const int sl = m * 16 + q4 + r;
            const bool dead = (kb + sl > qabs) || ((pb >> sl) & 1ull);
            sc[m][n][r] = dead ? -1e30f : sc[m][n][r];
          }
      }
      float ps = 0.f;
#pragma unroll
      for (int m = 0; m < 4; ++m) {
        float p0 = exp2f(sc[m][n][0]);
        float p1 = exp2f(sc[m][n][1]);
        float p2 = exp2f(sc[m][n][2]);
        float p3 = exp2f(sc[m][n][3]);
        ps += (p0 + p1) + (p2 + p3);
        uint2 pk;  // truncation pack via v_perm
        pk.x = __builtin_amdgcn_perm(__float_as_uint(p1), __float_as_uint(p0), 0x07060302);
        pk.y = __builtin_amdgcn_perm(__float_as_uint(p3), __float_as_uint(p2), 0x07060302);
        *reinterpret_cast<uint2*>(Ps + (qrow + n * 16 + lr) * 72 + m * 16 + q4) = pk;
      }
      lo[n] += ps;
    }

    // O^T += V^T P^T (P from same-wave LDS rows; lgkmcnt ordering only)
#pragma unroll
    for (int n = 0; n < 2; ++n) {
      bf16x8 bp0 = *reinterpret_cast<const bf16x8*>(Ps + (qrow + n * 16 + lr) * 72 + q8);
      bf16x8 bp1 = *reinterpret_cast<const bf16x8*>(Ps + (qrow + n * 16 + lr) * 72 + 32 + q8);
#pragma unroll
      for (int md = 0; md < 4; ++md) {
        Oc[md][n] = __builtin_amdgcn_mfma_f32_16x16x32_bf16(av0[md], bp0, Oc[md][n], 0, 0, 0);
        Oc[md][n] = __builtin_amdgcn_mfma_f32_16x16x32_bf16(av1[md], bp1, Oc[md][n], 0, 0, 0);
      }
    }

#pragma unroll
    for (int m = 0; m < 4; ++m) { ak0[m] = nk0[m]; ak1[m] = nk1[m]; }
  }

  // epilogue: single cross-lane l reduction; O'[q][d] = O^T/l (bf16), l raw fp32
  const size_t obase = (size_t)slot * 4096;
#pragma unroll
  for (int n = 0; n < 2; ++n) {
    lo[n] += __shfl_xor(lo[n], 16, 64);
    lo[n] += __shfl_xor(lo[n], 32, 64);
    const float inv = 1.f / lo[n];
    const int qlocal = qrow + n * 16 + lr;
#pragma unroll
    for (int md = 0; md < 4; ++md) {
      uint2 pk;
      pk.x = (uint32_t)f2bf(Oc[md][n][0] * inv) | ((uint32_t)f2bf(Oc[md][n][1] * inv) << 16);
      pk.y = (uint32_t)f2bf(Oc[md][n][2] * inv) | ((uint32_t)f2bf(Oc[md][n][3] * inv) << 16);
      *reinterpret_cast<uint2*>(Opart + obase + (size_t)qlocal * 64 + md * 16 + q4) = pk;
    }
    if (ln < 16) Lpart[slot * 64 + qlocal] = lo[n];
  }
}

// merge partials: l-weighted average. block per (bh, qi); thread t: q=t>>2, 16 d at (t&3)*16
__global__ __launch_bounds__(256) void k_merge(
    const u16* __restrict__ Opart, const float* __restrict__ Lpart, u16* __restrict__ O) {
  const int bh = blockIdx.x >> 5, qi = blockIdx.x & 31;
  const int nc = (qi >> 3) + 1;
  const int band = qi >> 3;
  const int pre = (band == 0 ? 0 : band == 1 ? 8 : band == 2 ? 24 : 48) + (qi & 7) * (band + 1);
  const int slot0 = bh * 80 + pre;

  const int t = threadIdx.x;
  const int q = t >> 2, ds = (t & 3) * 16;

  float wc[4], wsum = 0.f;
  for (int cI = 0; cI < nc; ++cI) {
    wc[cI] = Lpart[(slot0 + cI) * 64 + q];
    wsum += wc[cI];
  }
  const float inv = 1.f / wsum;

  float acc[16];
#pragma unroll
  for (int e = 0; e < 16; ++e) acc[e] = 0.f;
  for (int cI = 0; cI < nc; ++cI) {
    const u16* src = Opart + (size_t)(slot0 + cI) * 4096 + q * 64 + ds;
    uint4 a = *reinterpret_cast<const uint4*>(src);
    uint4 b = *reinterpret_cast<const uint4*>(src + 8);
    uint32_t uu[8] = {a.x, a.y, a.z, a.w, b.x, b.y, b.z, b.w};
    const float wci = wc[cI];
#pragma unroll
    for (int p = 0; p < 8; ++p) {
      acc[2 * p]     += wci * __uint_as_float(uu[p] << 16);
      acc[2 * p + 1] += wci * __uint_as_float(uu[p] & 0xFFFF0000u);
    }
  }

  const int bI = bh >> 4, hI = bh & 15;
  const size_t row = (size_t)(bI * 2048 + qi * 64 + q);
  u16* dst = O + row * 1024 + hI * 64 + ds;
  uint32_t op[8];
#pragma unroll
  for (int p = 0; p < 8; ++p)
    op[p] = (uint32_t)f2bf(acc[2 * p] * inv) | ((uint32_t)f2bf(acc[2 * p + 1] * inv) << 16);
  *reinterpret_cast<uint4*>(dst) = *reinterpret_cast<const uint4*>(&op[0]);
  *reinterpret_cast<uint4*>(dst + 8) = *reinterpret_cast<const uint4*>(&op[4]);
}

// ---------------- launch ----------------

extern "C" void kernel_launch(void* const* d_in, const int* in_sizes, int n_in,
                              void* d_out, int out_size, void* d_ws, size_t ws_size,
                              hipStream_t stream) {
  (void)in_sizes; (void)n_in; (void)out_size; (void)ws_size;
  const float* batch = (const float*)d_in[0];
  const int* ids     = (const int*)d_in[1];
  const float* W_Q   = (const float*)d_in[2];
  const float* W_K   = (const float*)d_in[3];
  const float* W_V   = (const float*)d_in[4];
  const float* b_Q   = (const float*)d_in[5];
  const float* b_K   = (const float*)d_in[6];
  const float* b_V   = (const float*)d_in[7];
  const float* W_O   = (const float*)d_in[8];
  const float* b_O   = (const float*)d_in[9];
  float* out = (float*)d_out;

  u16* ws = (u16*)d_ws;
  u16* Xbf   = ws;                        // 4,194,304
  u16* WqkvT = Xbf + 4194304;             // 3,145,728 (dead after k_qkv)
  u16* WoT   = WqkvT + 3145728;           // 1,048,576
  u16* Qtb   = WoT + 1048576;             // 4,194,304 (tiled)
  u16* Ktb   = Qtb + 4194304;             // 4,194,304 (tiled)
  u16* Vtb   = Ktb + 4194304;             // 4,194,304 (tiled V^T)
  u16* Opart = Vtb + 4194304;             // 2560*4096 = 10,485,760
  float* Lpart = (float*)WqkvT;           // overlay dead WqkvT (163,840 f32)
  u16* Ob    = Xbf;                       // reuse X after k_qkv

  unsigned long long* padbits =
      (unsigned long long*)((char*)d_out + (size_t)out_size * 4 - 512);

  k_prologue<<<8208, 256, 0, stream>>>(batch, ids, W_Q, W_K, W_V, W_O, Xbf, WqkvT, WoT, padbits);
  k_qkv<<<dim3(32, 24), 256, 0, stream>>>(Xbf, WqkvT, b_Q, b_K, b_V, Qtb, Ktb, Vtb);
  k_attn<<<2560, 128, 0, stream>>>(Qtb, Ktb, Vtb, padbits, Opart, Lpart);
  k_merge<<<1024, 256, 0, stream>>>(Opart, Lpart, Ob);
  k_out<<<dim3(32, 8), 256, 0, stream>>>(Ob, WoT, b_O, out);
}